// Round 1
// baseline (886.501 us; speedup 1.0000x reference)
//
#include <hip/hip_runtime.h>
#include <hip/hip_bf16.h>

// Problem constants (SpGAT): N=50000 nodes, R=500 rels, E=800000 edges, D=128
#define N_NODES 50000
#define N_RELS  500
#define N_EDGES 800000
#define DIM     128

// ---------------------------------------------------------------------------
// build_B: B[k*256+j] = (j<128) ? a[j,k] : a[j-128, 128+k]
// so that proj[n,j] = sum_k ent[n,k] * B[k,j] gives [src_proj | dst_proj].
// ---------------------------------------------------------------------------
__global__ void build_B(const float* __restrict__ a, float* __restrict__ B) {
    int t = blockIdx.x * 256 + threadIdx.x;     // 0 .. 128*256-1
    int k = t >> 8, j = t & 255;
    B[t] = (j < 128) ? a[j * 384 + k] : a[(j - 128) * 384 + 128 + k];
}

// ---------------------------------------------------------------------------
// proj_kernel: proj(50000 x 256) = ent(50000 x 128) @ B(128 x 256), fp32.
// 8 nodes per block; thread j owns output column j. ent addresses are
// wave-uniform -> scalar loads; B loads coalesced across j.
// ---------------------------------------------------------------------------
__global__ __launch_bounds__(256) void proj_kernel(const float* __restrict__ ent,
                                                   const float* __restrict__ B,
                                                   float* __restrict__ proj) {
    const int j = threadIdx.x;
    const int node0 = blockIdx.x * 8;
    float acc[8];
#pragma unroll
    for (int nn = 0; nn < 8; nn++) acc[nn] = 0.f;

    for (int k4 = 0; k4 < DIM; k4 += 4) {
        const float b0 = B[(k4 + 0) * 256 + j];
        const float b1 = B[(k4 + 1) * 256 + j];
        const float b2 = B[(k4 + 2) * 256 + j];
        const float b3 = B[(k4 + 3) * 256 + j];
#pragma unroll
        for (int nn = 0; nn < 8; nn++) {
            const float4 ev = *(const float4*)(ent + (size_t)(node0 + nn) * DIM + k4);
            acc[nn] = fmaf(ev.x, b0, fmaf(ev.y, b1, fmaf(ev.z, b2, fmaf(ev.w, b3, acc[nn]))));
        }
    }
#pragma unroll
    for (int nn = 0; nn < 8; nn++)
        proj[(size_t)(node0 + nn) * 256 + j] = acc[nn];
}

// ---------------------------------------------------------------------------
// rel_kernel: one block per relation r (128 threads).
//   rel_proj[r,i] = sum_k rel[r,k] * a[i, 256+k]
//   out_rel[r,i]  = relu(sum_k rel[r,k] * W_r[k,i]) + rel[r,i]
// ---------------------------------------------------------------------------
__global__ __launch_bounds__(128) void rel_kernel(const float* __restrict__ rel,
                                                  const float* __restrict__ a,
                                                  const float* __restrict__ Wr,
                                                  float* __restrict__ rel_proj,
                                                  float* __restrict__ out_rel) {
    __shared__ float sR[DIM];
    const int r = blockIdx.x, i = threadIdx.x;
    sR[i] = rel[r * DIM + i];
    __syncthreads();
    float acc1 = 0.f, acc2 = 0.f;
    const float* arow = a + i * 384 + 256;
#pragma unroll 4
    for (int k = 0; k < DIM; k++) {
        acc1 = fmaf(sR[k], arow[k], acc1);
        acc2 = fmaf(sR[k], Wr[k * DIM + i], acc2);
    }
    rel_proj[r * DIM + i] = acc1;
    out_rel[r * DIM + i] = fmaxf(acc2, 0.f) + sR[i];
}

// ---------------------------------------------------------------------------
// edge_kernel: one 64-lane wave per edge; lane handles dims {2l, 2l+1}.
//   m = src_proj[row] + dst_proj[col] + rel_proj[rid]
//   e = exp(-leaky_relu(m . a_2, 0.2))
//   atomically accumulate e*m into h_num[row], e into rowsum[row]
// ---------------------------------------------------------------------------
__global__ __launch_bounds__(256) void edge_kernel(const int* __restrict__ edges,
                                                   const int* __restrict__ rels,
                                                   const float* __restrict__ proj,
                                                   const float* __restrict__ relp,
                                                   const float* __restrict__ a2,
                                                   float* __restrict__ hnum,
                                                   float* __restrict__ rowsum) {
    const int wave = threadIdx.x >> 6;
    const int lane = threadIdx.x & 63;
    const int e = blockIdx.x * 4 + wave;
    if (e >= N_EDGES) return;

    const int row = edges[e];
    const int col = edges[N_EDGES + e];
    const int rid = rels[e];
    const int d = lane * 2;

    const float2 s  = *(const float2*)(proj + (size_t)row * 256 + d);
    const float2 t  = *(const float2*)(proj + (size_t)col * 256 + 128 + d);
    const float2 rv = *(const float2*)(relp + (size_t)rid * DIM + d);

    const float m0 = s.x + t.x + rv.x;
    const float m1 = s.y + t.y + rv.y;

    const float2 a2v = *(const float2*)(a2 + d);
    float p = m0 * a2v.x + m1 * a2v.y;
#pragma unroll
    for (int m = 32; m >= 1; m >>= 1) p += __shfl_xor(p, m, 64);

    const float pw = (p > 0.f) ? -p : -0.2f * p;   // -leaky_relu(p, 0.2)
    const float ev = __expf(pw);

    float* hp = hnum + (size_t)row * DIM + d;
    unsafeAtomicAdd(hp,     ev * m0);
    unsafeAtomicAdd(hp + 1, ev * m1);
    if (lane == 0) unsafeAtomicAdd(rowsum + row, ev);
}

// ---------------------------------------------------------------------------
// finalize: out_ent = relu(h_num / (rowsum + 1e-12))   [relu(elu(x)) == relu(x)]
// ---------------------------------------------------------------------------
__global__ __launch_bounds__(256) void finalize_kernel(float* __restrict__ out,
                                                       const float* __restrict__ rowsum) {
    const int i = blockIdx.x * 256 + threadIdx.x;
    if (i < N_NODES * DIM) {
        const float rs = rowsum[i >> 7];
        out[i] = fmaxf(out[i] / (rs + 1e-12f), 0.f);
    }
}

extern "C" void kernel_launch(void* const* d_in, const int* in_sizes, int n_in,
                              void* d_out, int out_size, void* d_ws, size_t ws_size,
                              hipStream_t stream) {
    const float* ent  = (const float*)d_in[0];   // 50000 x 128
    const float* rel  = (const float*)d_in[1];   // 500 x 128
    const int*   edges = (const int*)d_in[2];    // 2 x 800000
    const int*   rels  = (const int*)d_in[3];    // 800000
    const float* a    = (const float*)d_in[4];   // 128 x 384
    const float* a2   = (const float*)d_in[5];   // 128
    const float* Wr   = (const float*)d_in[6];   // 128 x 128

    float* out_ent = (float*)d_out;                       // 50000*128
    float* out_rel = (float*)d_out + N_NODES * DIM;       // 500*128

    // Workspace layout (floats): proj | rel_proj | B | rowsum
    float* proj   = (float*)d_ws;                         // 50000*256 = 12.8M
    float* relp   = proj + (size_t)N_NODES * 256;         // 500*128   = 64000
    float* B      = relp + N_RELS * DIM;                  // 128*256   = 32768
    float* rowsum = B + 128 * 256;                        // 50000

    // h_num accumulates in d_out's out_ent region -> must be zeroed (0xAA poison).
    hipMemsetAsync(out_ent, 0, (size_t)N_NODES * DIM * sizeof(float), stream);
    hipMemsetAsync(rowsum, 0, N_NODES * sizeof(float), stream);

    build_B<<<128, 256, 0, stream>>>(a, B);
    proj_kernel<<<N_NODES / 8, 256, 0, stream>>>(ent, B, proj);
    rel_kernel<<<N_RELS, 128, 0, stream>>>(rel, a, Wr, relp, out_rel);
    edge_kernel<<<N_EDGES / 4, 256, 0, stream>>>(edges, rels, proj, relp, a2,
                                                 out_ent, rowsum);
    finalize_kernel<<<(N_NODES * DIM + 255) / 256, 256, 0, stream>>>(out_ent, rowsum);
}

// Round 2
// 480.902 us; speedup vs baseline: 1.8434x; 1.8434x over previous
//
#include <hip/hip_runtime.h>
#include <hip/hip_bf16.h>

// Problem constants (SpGAT): N=50000 nodes, R=500 rels, E=800000 edges, D=128
#define N_NODES 50000
#define N_RELS  500
#define N_EDGES 800000
#define DIM     128

// ---------------------------------------------------------------------------
// build_B: B[k*256+j] = (j<128) ? a[j,k] : a[j-128, 128+k]
// so that proj[n,j] = sum_k ent[n,k] * B[k,j] gives [src_proj | dst_proj].
// ---------------------------------------------------------------------------
__global__ void build_B(const float* __restrict__ a, float* __restrict__ B) {
    int t = blockIdx.x * 256 + threadIdx.x;     // 0 .. 128*256-1
    int k = t >> 8, j = t & 255;
    B[t] = (j < 128) ? a[j * 384 + k] : a[(j - 128) * 384 + 128 + k];
}

// ---------------------------------------------------------------------------
// proj_kernel: proj(50000 x 256) = ent(50000 x 128) @ B(128 x 256), fp32.
// ---------------------------------------------------------------------------
__global__ __launch_bounds__(256) void proj_kernel(const float* __restrict__ ent,
                                                   const float* __restrict__ B,
                                                   float* __restrict__ proj) {
    const int j = threadIdx.x;
    const int node0 = blockIdx.x * 8;
    float acc[8];
#pragma unroll
    for (int nn = 0; nn < 8; nn++) acc[nn] = 0.f;

    for (int k4 = 0; k4 < DIM; k4 += 4) {
        const float b0 = B[(k4 + 0) * 256 + j];
        const float b1 = B[(k4 + 1) * 256 + j];
        const float b2 = B[(k4 + 2) * 256 + j];
        const float b3 = B[(k4 + 3) * 256 + j];
#pragma unroll
        for (int nn = 0; nn < 8; nn++) {
            const float4 ev = *(const float4*)(ent + (size_t)(node0 + nn) * DIM + k4);
            acc[nn] = fmaf(ev.x, b0, fmaf(ev.y, b1, fmaf(ev.z, b2, fmaf(ev.w, b3, acc[nn]))));
        }
    }
#pragma unroll
    for (int nn = 0; nn < 8; nn++)
        proj[(size_t)(node0 + nn) * 256 + j] = acc[nn];
}

// ---------------------------------------------------------------------------
// rel_kernel: one block per relation r (128 threads).
// ---------------------------------------------------------------------------
__global__ __launch_bounds__(128) void rel_kernel(const float* __restrict__ rel,
                                                  const float* __restrict__ a,
                                                  const float* __restrict__ Wr,
                                                  float* __restrict__ rel_proj,
                                                  float* __restrict__ out_rel) {
    __shared__ float sR[DIM];
    const int r = blockIdx.x, i = threadIdx.x;
    sR[i] = rel[r * DIM + i];
    __syncthreads();
    float acc1 = 0.f, acc2 = 0.f;
    const float* arow = a + i * 384 + 256;
#pragma unroll 4
    for (int k = 0; k < DIM; k++) {
        acc1 = fmaf(sR[k], arow[k], acc1);
        acc2 = fmaf(sR[k], Wr[k * DIM + i], acc2);
    }
    rel_proj[r * DIM + i] = acc1;
    out_rel[r * DIM + i] = fmaxf(acc2, 0.f) + sR[i];
}

// ---------------------------------------------------------------------------
// CSR build pass 1: histogram of destination segment (row).
// ---------------------------------------------------------------------------
__global__ __launch_bounds__(256) void count_kernel(const int* __restrict__ edges,
                                                    int* __restrict__ count) {
    const int e = blockIdx.x * 256 + threadIdx.x;
    if (e < N_EDGES) atomicAdd(&count[edges[e]], 1);
}

// ---------------------------------------------------------------------------
// CSR build pass 2: exclusive scan over 50000 counts (single 1024-thread block).
// Writes start[0..N] and a scratch copy cursor[0..N-1] for the scatter pass.
// ---------------------------------------------------------------------------
#define SCAN_CHUNK 49   // 1024 * 49 = 50176 >= 50000
__global__ __launch_bounds__(1024) void scan_kernel(const int* __restrict__ count,
                                                    int* __restrict__ start,
                                                    int* __restrict__ cursor) {
    __shared__ int part[1024];
    const int t = threadIdx.x;
    const int lo = t * SCAN_CHUNK;
    const int hi = min(lo + SCAN_CHUNK, N_NODES);
    int sum = 0;
    for (int i = lo; i < hi; i++) sum += count[i];
    part[t] = sum;
    __syncthreads();
    // Hillis-Steele inclusive scan over 1024 partials
    for (int off = 1; off < 1024; off <<= 1) {
        int v = (t >= off) ? part[t - off] : 0;
        __syncthreads();
        part[t] += v;
        __syncthreads();
    }
    int base = (t == 0) ? 0 : part[t - 1];
    for (int i = lo; i < hi; i++) {
        start[i] = base;
        cursor[i] = base;
        base += count[i];
    }
    if (t == 1023) start[N_NODES] = part[1023];
}

// ---------------------------------------------------------------------------
// CSR build pass 3: scatter (col, rel) into row-sorted order.
// ---------------------------------------------------------------------------
__global__ __launch_bounds__(256) void scatter_kernel(const int* __restrict__ edges,
                                                      const int* __restrict__ rels,
                                                      int* __restrict__ cursor,
                                                      int2* __restrict__ edat) {
    const int e = blockIdx.x * 256 + threadIdx.x;
    if (e < N_EDGES) {
        const int row = edges[e];
        const int pos = atomicAdd(&cursor[row], 1);
        edat[pos] = make_int2(edges[N_EDGES + e], rels[e]);
    }
}

// ---------------------------------------------------------------------------
// gather_kernel: one 64-lane wave per node; lane owns dims {2l, 2l+1}.
// Walks the node's CSR segment, accumulates h_num / e_rowsum in registers,
// writes out_ent = relu(h_num / (rowsum + eps)) exactly once. No atomics.
// ---------------------------------------------------------------------------
__global__ __launch_bounds__(256) void gather_kernel(const int* __restrict__ start,
                                                     const int2* __restrict__ edat,
                                                     const float* __restrict__ proj,
                                                     const float* __restrict__ relp,
                                                     const float* __restrict__ a2,
                                                     float* __restrict__ out) {
    const int wave = threadIdx.x >> 6;
    const int lane = threadIdx.x & 63;
    const int n = blockIdx.x * 4 + wave;
    if (n >= N_NODES) return;

    const int s = start[n];
    const int e = start[n + 1];
    const int d = lane * 2;

    const float2 sp  = *(const float2*)(proj + (size_t)n * 256 + d);   // src_proj[n]
    const float2 a2v = *(const float2*)(a2 + d);

    float acc0 = 0.f, acc1 = 0.f, esum = 0.f;
    for (int i = s; i < e; i++) {
        const int2 cd = edat[i];                                        // wave-uniform
        const float2 t  = *(const float2*)(proj + (size_t)cd.x * 256 + 128 + d);
        const float2 rv = *(const float2*)(relp + (size_t)cd.y * DIM + d);
        const float m0 = sp.x + t.x + rv.x;
        const float m1 = sp.y + t.y + rv.y;
        float p = m0 * a2v.x + m1 * a2v.y;
#pragma unroll
        for (int m = 32; m >= 1; m >>= 1) p += __shfl_xor(p, m, 64);    // full-wave sum
        const float pw = (p > 0.f) ? -p : -0.2f * p;                    // -leaky_relu
        const float ev = __expf(pw);
        acc0 = fmaf(ev, m0, acc0);
        acc1 = fmaf(ev, m1, acc1);
        esum += ev;                                                     // wave-uniform
    }
    const float inv = 1.f / (esum + 1e-12f);
    float* op = out + (size_t)n * DIM + d;
    op[0] = fmaxf(acc0 * inv, 0.f);   // relu(elu(x)) == relu(x)
    op[1] = fmaxf(acc1 * inv, 0.f);
}

extern "C" void kernel_launch(void* const* d_in, const int* in_sizes, int n_in,
                              void* d_out, int out_size, void* d_ws, size_t ws_size,
                              hipStream_t stream) {
    const float* ent  = (const float*)d_in[0];   // 50000 x 128
    const float* rel  = (const float*)d_in[1];   // 500 x 128
    const int*   edges = (const int*)d_in[2];    // 2 x 800000
    const int*   rels  = (const int*)d_in[3];    // 800000
    const float* a    = (const float*)d_in[4];   // 128 x 384
    const float* a2   = (const float*)d_in[5];   // 128
    const float* Wr   = (const float*)d_in[6];   // 128 x 128

    float* out_ent = (float*)d_out;                       // 50000*128
    float* out_rel = (float*)d_out + N_NODES * DIM;       // 500*128

    // Workspace layout: proj | relp | B | edat(int2) | count | start | cursor
    float* proj   = (float*)d_ws;                         // 50000*256 floats
    float* relp   = proj + (size_t)N_NODES * 256;         // 500*128
    float* B      = relp + N_RELS * DIM;                  // 128*256
    int2*  edat   = (int2*)(B + 128 * 256);               // 800000 int2 (8B-aligned)
    int*   count  = (int*)(edat + N_EDGES);               // 50000
    int*   start  = count + N_NODES;                      // 50001
    int*   cursor = start + N_NODES + 1;                  // 50000

    hipMemsetAsync(count, 0, N_NODES * sizeof(int), stream);

    build_B<<<128, 256, 0, stream>>>(a, B);
    proj_kernel<<<N_NODES / 8, 256, 0, stream>>>(ent, B, proj);
    rel_kernel<<<N_RELS, 128, 0, stream>>>(rel, a, Wr, relp, out_rel);

    count_kernel<<<(N_EDGES + 255) / 256, 256, 0, stream>>>(edges, count);
    scan_kernel<<<1, 1024, 0, stream>>>(count, start, cursor);
    scatter_kernel<<<(N_EDGES + 255) / 256, 256, 0, stream>>>(edges, rels, cursor, edat);

    gather_kernel<<<(N_NODES + 3) / 4, 256, 0, stream>>>(start, edat, proj, relp, a2,
                                                         out_ent);
}

// Round 3
// 423.592 us; speedup vs baseline: 2.0928x; 1.1353x over previous
//
#include <hip/hip_runtime.h>
#include <hip/hip_bf16.h>

// Problem constants (SpGAT): N=50000 nodes, R=500 rels, E=800000 edges, D=128
#define N_NODES 50000
#define N_RELS  500
#define N_EDGES 800000
#define DIM     128

// ---------------------------------------------------------------------------
// build_B: B[k*256+j] = (j<128) ? a[j,k] : a[j-128, 128+k]
// proj[n,j] = sum_k ent[n,k] * B[k,j] gives [src_proj | dst_proj].
// ---------------------------------------------------------------------------
__global__ void build_B(const float* __restrict__ a, float* __restrict__ B) {
    int t = blockIdx.x * 256 + threadIdx.x;     // 0 .. 128*256-1
    int k = t >> 8, j = t & 255;
    B[t] = (j < 128) ? a[j * 384 + k] : a[(j - 128) * 384 + 128 + k];
}

// ---------------------------------------------------------------------------
// proj_kernel: 8 nodes/block. Thread j owns output column j.
//   j <  128 : src_proj column j  -> projS (fp32, used by the node itself)
//   j >= 128 : dst_proj column j-128 -> projD (bf16, randomly gathered later)
// Fused: per-node dots  sdot[n] = src_proj[n].a2, ddot[n] = dst_proj[n].a2
// via per-wave shfl reduction (waves 0,1 = src half; waves 2,3 = dst half).
// ---------------------------------------------------------------------------
__global__ __launch_bounds__(256) void proj_kernel(const float* __restrict__ ent,
                                                   const float* __restrict__ B,
                                                   const float* __restrict__ a2,
                                                   float* __restrict__ projS,
                                                   __hip_bfloat16* __restrict__ projD,
                                                   float* __restrict__ sdot,
                                                   float* __restrict__ ddot) {
    const int j = threadIdx.x;
    const int node0 = blockIdx.x * 8;
    float acc[8];
#pragma unroll
    for (int nn = 0; nn < 8; nn++) acc[nn] = 0.f;

    for (int k4 = 0; k4 < DIM; k4 += 4) {
        const float b0 = B[(k4 + 0) * 256 + j];
        const float b1 = B[(k4 + 1) * 256 + j];
        const float b2 = B[(k4 + 2) * 256 + j];
        const float b3 = B[(k4 + 3) * 256 + j];
#pragma unroll
        for (int nn = 0; nn < 8; nn++) {
            const float4 ev = *(const float4*)(ent + (size_t)(node0 + nn) * DIM + k4);
            acc[nn] = fmaf(ev.x, b0, fmaf(ev.y, b1, fmaf(ev.z, b2, fmaf(ev.w, b3, acc[nn]))));
        }
    }

    if (j < 128) {
#pragma unroll
        for (int nn = 0; nn < 8; nn++)
            projS[(size_t)(node0 + nn) * DIM + j] = acc[nn];
    } else {
#pragma unroll
        for (int nn = 0; nn < 8; nn++)
            projD[(size_t)(node0 + nn) * DIM + (j - 128)] = __float2bfloat16(acc[nn]);
    }

    // fused dot products with a2
    const float aw = a2[j & 127];
    float w[8];
#pragma unroll
    for (int nn = 0; nn < 8; nn++) {
        float v = acc[nn] * aw;
#pragma unroll
        for (int m = 32; m >= 1; m >>= 1) v += __shfl_xor(v, m, 64);
        w[nn] = v;
    }
    __shared__ float red[4][8];
    if ((j & 63) == 0) {
#pragma unroll
        for (int nn = 0; nn < 8; nn++) red[j >> 6][nn] = w[nn];
    }
    __syncthreads();
    if (j < 8)            sdot[node0 + j]       = red[0][j] + red[1][j];
    else if (j < 16)      ddot[node0 + (j - 8)] = red[2][j - 8] + red[3][j - 8];
}

// ---------------------------------------------------------------------------
// rel_kernel: one block per relation r. Fused rdot[r] = rel_proj[r].a2.
// ---------------------------------------------------------------------------
__global__ __launch_bounds__(128) void rel_kernel(const float* __restrict__ rel,
                                                  const float* __restrict__ a,
                                                  const float* __restrict__ Wr,
                                                  const float* __restrict__ a2,
                                                  float* __restrict__ rel_proj,
                                                  float* __restrict__ rdot,
                                                  float* __restrict__ out_rel) {
    __shared__ float sR[DIM];
    __shared__ float rp[2];
    const int r = blockIdx.x, i = threadIdx.x;
    sR[i] = rel[r * DIM + i];
    __syncthreads();
    float acc1 = 0.f, acc2 = 0.f;
    const float* arow = a + i * 384 + 256;
#pragma unroll 4
    for (int k = 0; k < DIM; k++) {
        acc1 = fmaf(sR[k], arow[k], acc1);
        acc2 = fmaf(sR[k], Wr[k * DIM + i], acc2);
    }
    rel_proj[r * DIM + i] = acc1;
    out_rel[r * DIM + i] = fmaxf(acc2, 0.f) + sR[i];

    float v = acc1 * a2[i];
#pragma unroll
    for (int m = 32; m >= 1; m >>= 1) v += __shfl_xor(v, m, 64);
    if ((i & 63) == 0) rp[i >> 6] = v;
    __syncthreads();
    if (i == 0) rdot[r] = rp[0] + rp[1];
}

// ---------------------------------------------------------------------------
// CSR build pass 1: histogram of rows.
// ---------------------------------------------------------------------------
__global__ __launch_bounds__(256) void count_kernel(const int* __restrict__ edges,
                                                    int* __restrict__ count) {
    const int e = blockIdx.x * 256 + threadIdx.x;
    if (e < N_EDGES) atomicAdd(&count[edges[e]], 1);
}

// ---------------------------------------------------------------------------
// CSR build pass 2: exclusive scan (single 1024-thread block).
// ---------------------------------------------------------------------------
#define SCAN_CHUNK 49   // 1024 * 49 = 50176 >= 50000
__global__ __launch_bounds__(1024) void scan_kernel(const int* __restrict__ count,
                                                    int* __restrict__ start,
                                                    int* __restrict__ cursor) {
    __shared__ int part[1024];
    const int t = threadIdx.x;
    const int lo = t * SCAN_CHUNK;
    const int hi = min(lo + SCAN_CHUNK, N_NODES);
    int sum = 0;
    for (int i = lo; i < hi; i++) sum += count[i];
    part[t] = sum;
    __syncthreads();
    for (int off = 1; off < 1024; off <<= 1) {
        int v = (t >= off) ? part[t - off] : 0;
        __syncthreads();
        part[t] += v;
        __syncthreads();
    }
    int base = (t == 0) ? 0 : part[t - 1];
    for (int i = lo; i < hi; i++) {
        start[i] = base;
        cursor[i] = base;
        base += count[i];
    }
    if (t == 1023) start[N_NODES] = part[1023];
}

// ---------------------------------------------------------------------------
// CSR build pass 3: scatter. Computes the attention weight ev per edge HERE
// (p = sdot[row]+ddot[col]+rdot[rid] by linearity of the dot) and packs
// (col | rid<<16, ev) into 8 bytes.
// ---------------------------------------------------------------------------
__global__ __launch_bounds__(256) void scatter_kernel(const int* __restrict__ edges,
                                                      const int* __restrict__ rels,
                                                      const float* __restrict__ sdot,
                                                      const float* __restrict__ ddot,
                                                      const float* __restrict__ rdot,
                                                      int* __restrict__ cursor,
                                                      int2* __restrict__ edat) {
    const int e = blockIdx.x * 256 + threadIdx.x;
    if (e < N_EDGES) {
        const int row = edges[e];
        const int col = edges[N_EDGES + e];
        const int rid = rels[e];
        const float p = sdot[row] + ddot[col] + rdot[rid];
        const float pw = (p > 0.f) ? -p : -0.2f * p;       // -leaky_relu(p, 0.2)
        const float ev = __expf(pw);
        const int pos = atomicAdd(&cursor[row], 1);
        edat[pos] = make_int2(col | (rid << 16), __float_as_int(ev));
    }
}

// ---------------------------------------------------------------------------
// gather_kernel: one wave per node, lane owns dims {2l, 2l+1}.
// Per edge: unpack (col,rid,ev); acc += ev*(t+rv). src part folded in once at
// the end: h_num = acc + sp*esum. Unrolled x2 for load ILP. No shfl, no exp.
// ---------------------------------------------------------------------------
__global__ __launch_bounds__(256) void gather_kernel(const int* __restrict__ start,
                                                     const int2* __restrict__ edat,
                                                     const unsigned short* __restrict__ projD,
                                                     const float* __restrict__ relp,
                                                     const float* __restrict__ projS,
                                                     float* __restrict__ out) {
    const int wave = threadIdx.x >> 6;
    const int lane = threadIdx.x & 63;
    const int n = blockIdx.x * 4 + wave;
    if (n >= N_NODES) return;

    const int s = start[n];
    const int e = start[n + 1];
    const int d = lane * 2;

    float acc0 = 0.f, acc1 = 0.f, esum = 0.f;
    int i = s;
    for (; i + 1 < e; i += 2) {
        const int2 c0 = edat[i];
        const int2 c1 = edat[i + 1];
        const unsigned u0 = *(const unsigned*)(projD + (((size_t)(c0.x & 0xFFFF)) << 7) + d);
        const unsigned u1 = *(const unsigned*)(projD + (((size_t)(c1.x & 0xFFFF)) << 7) + d);
        const float2 r0 = *(const float2*)(relp + ((c0.x >> 16) << 7) + d);
        const float2 r1 = *(const float2*)(relp + ((c1.x >> 16) << 7) + d);
        const float e0 = __int_as_float(c0.y);
        const float e1 = __int_as_float(c1.y);
        acc0 = fmaf(e0, __uint_as_float(u0 << 16) + r0.x, acc0);
        acc1 = fmaf(e0, __uint_as_float(u0 & 0xFFFF0000u) + r0.y, acc1);
        acc0 = fmaf(e1, __uint_as_float(u1 << 16) + r1.x, acc0);
        acc1 = fmaf(e1, __uint_as_float(u1 & 0xFFFF0000u) + r1.y, acc1);
        esum += e0 + e1;
    }
    if (i < e) {
        const int2 c0 = edat[i];
        const unsigned u0 = *(const unsigned*)(projD + (((size_t)(c0.x & 0xFFFF)) << 7) + d);
        const float2 r0 = *(const float2*)(relp + ((c0.x >> 16) << 7) + d);
        const float e0 = __int_as_float(c0.y);
        acc0 = fmaf(e0, __uint_as_float(u0 << 16) + r0.x, acc0);
        acc1 = fmaf(e0, __uint_as_float(u0 & 0xFFFF0000u) + r0.y, acc1);
        esum += e0;
    }
    const float inv = 1.f / (esum + 1e-12f);
    const float2 sp = *(const float2*)(projS + ((size_t)n << 7) + d);
    float* op = out + ((size_t)n << 7) + d;
    op[0] = fmaxf(fmaf(sp.x, esum, acc0) * inv, 0.f);   // relu(elu(x)) == relu(x)
    op[1] = fmaxf(fmaf(sp.y, esum, acc1) * inv, 0.f);
}

extern "C" void kernel_launch(void* const* d_in, const int* in_sizes, int n_in,
                              void* d_out, int out_size, void* d_ws, size_t ws_size,
                              hipStream_t stream) {
    const float* ent  = (const float*)d_in[0];   // 50000 x 128
    const float* rel  = (const float*)d_in[1];   // 500 x 128
    const int*   edges = (const int*)d_in[2];    // 2 x 800000
    const int*   rels  = (const int*)d_in[3];    // 800000
    const float* a    = (const float*)d_in[4];   // 128 x 384
    const float* a2   = (const float*)d_in[5];   // 128
    const float* Wr   = (const float*)d_in[6];   // 128 x 128

    float* out_ent = (float*)d_out;                       // 50000*128
    float* out_rel = (float*)d_out + N_NODES * DIM;       // 500*128

    // Workspace layout
    float* projS = (float*)d_ws;                          // 50000*128 f32
    float* relp  = projS + (size_t)N_NODES * DIM;         // 500*128
    float* B     = relp + N_RELS * DIM;                   // 128*256
    float* sdot  = B + 128 * 256;                         // 50000
    float* ddot  = sdot + N_NODES;                        // 50000
    float* rdot  = ddot + N_NODES;                        // 500
    int2*  edat  = (int2*)(rdot + N_RELS + 4);            // 800000 int2 (8B aligned)
    unsigned short* projD = (unsigned short*)(edat + N_EDGES); // 50000*128 bf16
    int*   count  = (int*)(projD + (size_t)N_NODES * DIM);     // 50000
    int*   startp = count + N_NODES;                      // 50001
    int*   cursor = startp + N_NODES + 1;                 // 50000

    hipMemsetAsync(count, 0, N_NODES * sizeof(int), stream);

    build_B<<<128, 256, 0, stream>>>(a, B);
    proj_kernel<<<N_NODES / 8, 256, 0, stream>>>(ent, B, a2, projS,
                                                 (__hip_bfloat16*)projD, sdot, ddot);
    rel_kernel<<<N_RELS, 128, 0, stream>>>(rel, a, Wr, a2, relp, rdot, out_rel);

    count_kernel<<<(N_EDGES + 255) / 256, 256, 0, stream>>>(edges, count);
    scan_kernel<<<1, 1024, 0, stream>>>(count, startp, cursor);
    scatter_kernel<<<(N_EDGES + 255) / 256, 256, 0, stream>>>(edges, rels, sdot, ddot,
                                                              rdot, cursor, edat);

    gather_kernel<<<(N_NODES + 3) / 4, 256, 0, stream>>>(startp, edat, projD, relp,
                                                         projS, out_ent);
}

// Round 4
// 318.171 us; speedup vs baseline: 2.7862x; 1.3313x over previous
//
#include <hip/hip_runtime.h>
#include <hip/hip_bf16.h>

// Problem constants (SpGAT): N=50000 nodes, R=500 rels, E=800000 edges, D=128
#define N_NODES 50000
#define N_RELS  500
#define N_EDGES 800000
#define DIM     128
#define N_PAD   50176           // 49 * 1024, zero-padded scan domain
#define SCAN_BLOCKS 49

// ---------------------------------------------------------------------------
// build_B: B[k*256+j] = (j<128) ? a[j,k] : a[j-128, 128+k]
// proj[n,j] = sum_k ent[n,k] * B[k,j] gives [src_proj | dst_proj].
// ---------------------------------------------------------------------------
__global__ void build_B(const float* __restrict__ a, float* __restrict__ B) {
    int t = blockIdx.x * 256 + threadIdx.x;     // 0 .. 128*256-1
    int k = t >> 8, j = t & 255;
    B[t] = (j < 128) ? a[j * 384 + k] : a[(j - 128) * 384 + 128 + k];
}

// ---------------------------------------------------------------------------
// proj_kernel: 8 nodes/block. Thread j owns output column j.
//   j <  128 : src_proj column j  -> projS (fp32)
//   j >= 128 : dst_proj column j-128 -> projD (bf16, randomly gathered later)
// Fused per-node dots sdot = src_proj.a2, ddot = dst_proj.a2.
// ---------------------------------------------------------------------------
__global__ __launch_bounds__(256) void proj_kernel(const float* __restrict__ ent,
                                                   const float* __restrict__ B,
                                                   const float* __restrict__ a2,
                                                   float* __restrict__ projS,
                                                   __hip_bfloat16* __restrict__ projD,
                                                   float* __restrict__ sdot,
                                                   float* __restrict__ ddot) {
    const int j = threadIdx.x;
    const int node0 = blockIdx.x * 8;
    float acc[8];
#pragma unroll
    for (int nn = 0; nn < 8; nn++) acc[nn] = 0.f;

    for (int k4 = 0; k4 < DIM; k4 += 4) {
        const float b0 = B[(k4 + 0) * 256 + j];
        const float b1 = B[(k4 + 1) * 256 + j];
        const float b2 = B[(k4 + 2) * 256 + j];
        const float b3 = B[(k4 + 3) * 256 + j];
#pragma unroll
        for (int nn = 0; nn < 8; nn++) {
            const float4 ev = *(const float4*)(ent + (size_t)(node0 + nn) * DIM + k4);
            acc[nn] = fmaf(ev.x, b0, fmaf(ev.y, b1, fmaf(ev.z, b2, fmaf(ev.w, b3, acc[nn]))));
        }
    }

    if (j < 128) {
#pragma unroll
        for (int nn = 0; nn < 8; nn++)
            projS[(size_t)(node0 + nn) * DIM + j] = acc[nn];
    } else {
#pragma unroll
        for (int nn = 0; nn < 8; nn++)
            projD[(size_t)(node0 + nn) * DIM + (j - 128)] = __float2bfloat16(acc[nn]);
    }

    const float aw = a2[j & 127];
    float w[8];
#pragma unroll
    for (int nn = 0; nn < 8; nn++) {
        float v = acc[nn] * aw;
#pragma unroll
        for (int m = 32; m >= 1; m >>= 1) v += __shfl_xor(v, m, 64);
        w[nn] = v;
    }
    __shared__ float red[4][8];
    if ((j & 63) == 0) {
#pragma unroll
        for (int nn = 0; nn < 8; nn++) red[j >> 6][nn] = w[nn];
    }
    __syncthreads();
    if (j < 8)            sdot[node0 + j]       = red[0][j] + red[1][j];
    else if (j < 16)      ddot[node0 + (j - 8)] = red[2][j - 8] + red[3][j - 8];
}

// ---------------------------------------------------------------------------
// rel_kernel: one block per relation r. Fused rdot[r] = rel_proj[r].a2.
// ---------------------------------------------------------------------------
__global__ __launch_bounds__(128) void rel_kernel(const float* __restrict__ rel,
                                                  const float* __restrict__ a,
                                                  const float* __restrict__ Wr,
                                                  const float* __restrict__ a2,
                                                  float* __restrict__ rel_proj,
                                                  float* __restrict__ rdot,
                                                  float* __restrict__ out_rel) {
    __shared__ float sR[DIM];
    __shared__ float rp[2];
    const int r = blockIdx.x, i = threadIdx.x;
    sR[i] = rel[r * DIM + i];
    __syncthreads();
    float acc1 = 0.f, acc2 = 0.f;
    const float* arow = a + i * 384 + 256;
#pragma unroll 4
    for (int k = 0; k < DIM; k++) {
        acc1 = fmaf(sR[k], arow[k], acc1);
        acc2 = fmaf(sR[k], Wr[k * DIM + i], acc2);
    }
    rel_proj[r * DIM + i] = acc1;
    out_rel[r * DIM + i] = fmaxf(acc2, 0.f) + sR[i];

    float v = acc1 * a2[i];
#pragma unroll
    for (int m = 32; m >= 1; m >>= 1) v += __shfl_xor(v, m, 64);
    if ((i & 63) == 0) rp[i >> 6] = v;
    __syncthreads();
    if (i == 0) rdot[r] = rp[0] + rp[1];
}

// ---------------------------------------------------------------------------
// CSR build pass 1: histogram of rows (count padded to N_PAD, pre-zeroed).
// ---------------------------------------------------------------------------
__global__ __launch_bounds__(256) void count_kernel(const int* __restrict__ edges,
                                                    int* __restrict__ count) {
    const int e = blockIdx.x * 256 + threadIdx.x;
    if (e < N_EDGES) atomicAdd(&count[edges[e]], 1);
}

// ---------------------------------------------------------------------------
// Parallel scan, phase 1: 49 blocks x 256 threads, 4 elems/thread (int4).
// Local exclusive positions -> locs; per-block total -> bsum.
// ---------------------------------------------------------------------------
__global__ __launch_bounds__(256) void scan_local(const int* __restrict__ count,
                                                  int* __restrict__ locs,
                                                  int* __restrict__ bsum) {
    __shared__ int sh[256];
    const int t = threadIdx.x;
    const int base = blockIdx.x * 1024 + t * 4;
    const int4 c = *(const int4*)(count + base);          // padded, no bounds check
    const int tot = c.x + c.y + c.z + c.w;
    sh[t] = tot;
    __syncthreads();
#pragma unroll
    for (int off = 1; off < 256; off <<= 1) {
        const int v = (t >= off) ? sh[t - off] : 0;
        __syncthreads();
        sh[t] += v;
        __syncthreads();
    }
    const int excl = (t == 0) ? 0 : sh[t - 1];
    int4 o;
    o.x = excl;
    o.y = o.x + c.x;
    o.z = o.y + c.y;
    o.w = o.z + c.z;
    *(int4*)(locs + base) = o;
    if (t == 255) bsum[blockIdx.x] = sh[255];
}

// ---------------------------------------------------------------------------
// Parallel scan, phase 2: one wave shfl-scans the 49 block totals -> exclusive.
// ---------------------------------------------------------------------------
__global__ __launch_bounds__(64) void scan_spine(int* __restrict__ bsum) {
    const int t = threadIdx.x;
    int v = (t < SCAN_BLOCKS) ? bsum[t] : 0;
    const int orig = v;
#pragma unroll
    for (int off = 1; off < 64; off <<= 1) {
        const int u = __shfl_up(v, off, 64);
        if (t >= off) v += u;
    }
    if (t < SCAN_BLOCKS) bsum[t] = v - orig;              // exclusive block offset
}

// ---------------------------------------------------------------------------
// Parallel scan, phase 3: add block offsets; write start & cursor.
// Padding zeros make start[50000] = N_EDGES automatically (block 48 tail).
// ---------------------------------------------------------------------------
__global__ __launch_bounds__(256) void scan_fixup(const int* __restrict__ locs,
                                                  const int* __restrict__ bsum,
                                                  int* __restrict__ start,
                                                  int* __restrict__ cursor) {
    const int base = blockIdx.x * 1024 + threadIdx.x * 4;
    const int off = bsum[blockIdx.x];
    int4 v = *(const int4*)(locs + base);
    v.x += off; v.y += off; v.z += off; v.w += off;
    *(int4*)(start + base) = v;
    *(int4*)(cursor + base) = v;
}

// ---------------------------------------------------------------------------
// CSR build pass 4: scatter. Computes attention weight ev per edge here
// (p = sdot[row] + ddot[col] + rdot[rid], by linearity) and packs
// (col | rid<<16, ev) into 8 bytes.
// ---------------------------------------------------------------------------
__global__ __launch_bounds__(256) void scatter_kernel(const int* __restrict__ edges,
                                                      const int* __restrict__ rels,
                                                      const float* __restrict__ sdot,
                                                      const float* __restrict__ ddot,
                                                      const float* __restrict__ rdot,
                                                      int* __restrict__ cursor,
                                                      int2* __restrict__ edat) {
    const int e = blockIdx.x * 256 + threadIdx.x;
    if (e < N_EDGES) {
        const int row = edges[e];
        const int col = edges[N_EDGES + e];
        const int rid = rels[e];
        const float p = sdot[row] + ddot[col] + rdot[rid];
        const float pw = (p > 0.f) ? -p : -0.2f * p;       // -leaky_relu(p, 0.2)
        const float ev = __expf(pw);
        const int pos = atomicAdd(&cursor[row], 1);
        edat[pos] = make_int2(col | (rid << 16), __float_as_int(ev));
    }
}

// ---------------------------------------------------------------------------
// gather_kernel: one wave per node, lane owns dims {2l, 2l+1}.
// ---------------------------------------------------------------------------
__global__ __launch_bounds__(256) void gather_kernel(const int* __restrict__ start,
                                                     const int2* __restrict__ edat,
                                                     const unsigned short* __restrict__ projD,
                                                     const float* __restrict__ relp,
                                                     const float* __restrict__ projS,
                                                     float* __restrict__ out) {
    const int wave = threadIdx.x >> 6;
    const int lane = threadIdx.x & 63;
    const int n = blockIdx.x * 4 + wave;
    if (n >= N_NODES) return;

    const int s = start[n];
    const int e = start[n + 1];
    const int d = lane * 2;

    float acc0 = 0.f, acc1 = 0.f, esum = 0.f;
    int i = s;
    for (; i + 1 < e; i += 2) {
        const int2 c0 = edat[i];
        const int2 c1 = edat[i + 1];
        const unsigned u0 = *(const unsigned*)(projD + (((size_t)(c0.x & 0xFFFF)) << 7) + d);
        const unsigned u1 = *(const unsigned*)(projD + (((size_t)(c1.x & 0xFFFF)) << 7) + d);
        const float2 r0 = *(const float2*)(relp + ((c0.x >> 16) << 7) + d);
        const float2 r1 = *(const float2*)(relp + ((c1.x >> 16) << 7) + d);
        const float e0 = __int_as_float(c0.y);
        const float e1 = __int_as_float(c1.y);
        acc0 = fmaf(e0, __uint_as_float(u0 << 16) + r0.x, acc0);
        acc1 = fmaf(e0, __uint_as_float(u0 & 0xFFFF0000u) + r0.y, acc1);
        acc0 = fmaf(e1, __uint_as_float(u1 << 16) + r1.x, acc0);
        acc1 = fmaf(e1, __uint_as_float(u1 & 0xFFFF0000u) + r1.y, acc1);
        esum += e0 + e1;
    }
    if (i < e) {
        const int2 c0 = edat[i];
        const unsigned u0 = *(const unsigned*)(projD + (((size_t)(c0.x & 0xFFFF)) << 7) + d);
        const float2 r0 = *(const float2*)(relp + ((c0.x >> 16) << 7) + d);
        const float e0 = __int_as_float(c0.y);
        acc0 = fmaf(e0, __uint_as_float(u0 << 16) + r0.x, acc0);
        acc1 = fmaf(e0, __uint_as_float(u0 & 0xFFFF0000u) + r0.y, acc1);
        esum += e0;
    }
    const float inv = 1.f / (esum + 1e-12f);
    const float2 sp = *(const float2*)(projS + ((size_t)n << 7) + d);
    float* op = out + ((size_t)n << 7) + d;
    op[0] = fmaxf(fmaf(sp.x, esum, acc0) * inv, 0.f);   // relu(elu(x)) == relu(x)
    op[1] = fmaxf(fmaf(sp.y, esum, acc1) * inv, 0.f);
}

extern "C" void kernel_launch(void* const* d_in, const int* in_sizes, int n_in,
                              void* d_out, int out_size, void* d_ws, size_t ws_size,
                              hipStream_t stream) {
    const float* ent  = (const float*)d_in[0];   // 50000 x 128
    const float* rel  = (const float*)d_in[1];   // 500 x 128
    const int*   edges = (const int*)d_in[2];    // 2 x 800000
    const int*   rels  = (const int*)d_in[3];    // 800000
    const float* a    = (const float*)d_in[4];   // 128 x 384
    const float* a2   = (const float*)d_in[5];   // 128
    const float* Wr   = (const float*)d_in[6];   // 128 x 128

    float* out_ent = (float*)d_out;                       // 50000*128
    float* out_rel = (float*)d_out + N_NODES * DIM;       // 500*128

    // Workspace layout (16B alignment maintained for int4/float4 users)
    float* projS = (float*)d_ws;                          // 50000*128 f32
    float* relp  = projS + (size_t)N_NODES * DIM;         // 500*128
    float* B     = relp + N_RELS * DIM;                   // 128*256
    float* sdot  = B + 128 * 256;                         // 50000
    float* ddot  = sdot + N_NODES;                        // 50000
    float* rdot  = ddot + N_NODES;                        // 500 (+4 pad)
    int2*  edat  = (int2*)(rdot + N_RELS + 4);            // 800000 int2
    unsigned short* projD = (unsigned short*)(edat + N_EDGES); // 50000*128 bf16
    int*   count  = (int*)(projD + (size_t)N_NODES * DIM);     // N_PAD
    int*   locs   = count + N_PAD;                        // N_PAD
    int*   bsum   = locs + N_PAD;                         // 64
    int*   startp = bsum + 64;                            // N_PAD (start[50000]=E)
    int*   cursor = startp + N_PAD;                       // N_PAD

    hipMemsetAsync(count, 0, N_PAD * sizeof(int), stream);

    build_B<<<128, 256, 0, stream>>>(a, B);
    proj_kernel<<<N_NODES / 8, 256, 0, stream>>>(ent, B, a2, projS,
                                                 (__hip_bfloat16*)projD, sdot, ddot);
    rel_kernel<<<N_RELS, 128, 0, stream>>>(rel, a, Wr, a2, relp, rdot, out_rel);

    count_kernel<<<(N_EDGES + 255) / 256, 256, 0, stream>>>(edges, count);
    scan_local<<<SCAN_BLOCKS, 256, 0, stream>>>(count, locs, bsum);
    scan_spine<<<1, 64, 0, stream>>>(bsum);
    scan_fixup<<<SCAN_BLOCKS, 256, 0, stream>>>(locs, bsum, startp, cursor);
    scatter_kernel<<<(N_EDGES + 255) / 256, 256, 0, stream>>>(edges, rels, sdot, ddot,
                                                              rdot, cursor, edat);

    gather_kernel<<<(N_NODES + 3) / 4, 256, 0, stream>>>(startp, edat, projD, relp,
                                                         projS, out_ent);
}